// Round 5
// baseline (227.605 us; speedup 1.0000x reference)
//
#include <hip/hip_runtime.h>
#include <math.h>

#define KDIM 100
#define DDIM 64

typedef __bf16 bf16x8 __attribute__((ext_vector_type(8)));
typedef float  f32x4  __attribute__((ext_vector_type(4)));
typedef float  f32x2  __attribute__((ext_vector_type(2)));

struct Weights {
  const float *w1, *b1, *w2, *b2, *w3, *b3, *w4, *b4, *w5, *b5;
};

// ---------------- LDS float offsets ----------------
constexpr int L_VEC = 0;      // [4][100] USUM, ISUM, US, IS
constexpr int L_PA  = 400;    // [4][128] PA1,PB1,PA2,PB2 (pads zeroed)
constexpr int L_B1  = 912;    // [2][128] b1 padded
constexpr int L_B2  = 1168;   // [2][64]
constexpr int L_B3  = 1296;   // [2][32]
constexpr int L_B4  = 1360;   // [2][16]
constexpr int L_W5  = 1392;   // [2][16]
constexpr int L_C   = 1424;   // [2][128] per-net row outputs
constexpr int L_H1F = 1680;   // h1 A-frags: 16 frags x 64 lanes x 16B (byte off 6720, 16B aligned)
constexpr int L_H2  = 5776;   // [64][66] f32
constexpr int L_H3  = 10000;  // [64][34] f32
constexpr int L_TOT = 12176;  // 48704 B

// ---------------- kernel 1: coalesced embedding row sums ----------------
__global__ void rowsum_kernel(const float* __restrict__ user_emb,
                              const float* __restrict__ item_emb,
                              float* __restrict__ u_rowsum,
                              float* __restrict__ i_rowsum,
                              int NU, int NI) {
  const int NR = NU + NI;
  const int lane  = threadIdx.x & 63;
  const int chunk = lane & 15, lrow = lane >> 4;
  const int gwave = (blockIdx.x * blockDim.x + threadIdx.x) >> 6;
  const int nwave = (gridDim.x * blockDim.x) >> 6;
  for (int base = gwave * 4; base < NR; base += nwave * 4) {
    const int r = base + lrow;
    float s = 0.f;
    if (r < NR) {
      const float* src = (r < NU) ? (user_emb + (size_t)r * DDIM)
                                  : (item_emb + (size_t)(r - NU) * DDIM);
      const float4 v = ((const float4*)src)[chunk];
      s = v.x + v.y + v.z + v.w;
    }
    s += __shfl_xor(s, 1); s += __shfl_xor(s, 2);
    s += __shfl_xor(s, 4); s += __shfl_xor(s, 8);
    if (chunk == 0 && r < NR) {
      if (r < NU) u_rowsum[r] = s; else i_rowsum[r - NU] = s;
    }
  }
}

// ---------------- kernel 2: MFMA GEMM-chain MLP ----------------
__global__ void __launch_bounds__(256) mlp_kernel(
    const int* __restrict__ user_idxs, const int* __restrict__ item_idxs,
    const int* __restrict__ uidx_t, const int* __restrict__ iidx_t,
    const float* __restrict__ uscr, const float* __restrict__ iscr,
    const float* __restrict__ u_rowsum, const float* __restrict__ i_rowsum,
    Weights N1, Weights N2, float* __restrict__ out)
{
  __shared__ float sm[L_TOT];
  const int tid  = threadIdx.x;
  const int lane = tid & 63;
  const int wv   = tid >> 6;     // wave 0..3
  const int g    = lane >> 4;    // k-group 0..3
  const int c16  = lane & 15;    // col/row-in-tile
  const int b    = blockIdx.x;

  // ---- W2/W3/W4 B-fragments in registers (K/N pads -> 0)
  bf16x8 W2f[2][4], W3f[2][2], W4f[2];
  #pragma unroll
  for (int net = 0; net < 2; ++net) {
    const Weights W = net ? N2 : N1;
    #pragma unroll
    for (int k = 0; k < 4; ++k) {
      #pragma unroll
      for (int i = 0; i < 8; ++i) {
        const int kk = 32 * k + 8 * g + i, nn = 16 * wv + c16;
        W2f[net][k][i] = (__bf16)((kk < 100 && nn < 50) ? W.w2[kk * 50 + nn] : 0.f);
      }
    }
    #pragma unroll
    for (int k = 0; k < 2; ++k) {
      #pragma unroll
      for (int i = 0; i < 8; ++i) {
        const int kk = 32 * k + 8 * g + i, nn = 16 * (wv & 1) + c16;
        W3f[net][k][i] = (__bf16)((kk < 50 && nn < 25) ? W.w3[kk * 25 + nn] : 0.f);
      }
    }
    #pragma unroll
    for (int i = 0; i < 8; ++i) {
      const int kk = 8 * g + i, nn = c16;
      W4f[net][i] = (__bf16)((kk < 25 && nn < 12) ? W.w4[kk * 12 + nn] : 0.f);
    }
  }

  // ---- phase 0: gathers + bias staging + PA pad zeroing
  if (tid < KDIM) {
    const int ub = user_idxs[b];
    const int idx = uidx_t[(size_t)ub * KDIM + tid];
    sm[L_VEC + 0 + tid]   = u_rowsum[idx];
    sm[L_VEC + 200 + tid] = uscr[(size_t)ub * KDIM + tid];
  } else if (tid >= 128 && tid < 128 + KDIM) {
    const int t = tid - 128;
    const int ib = item_idxs[b];
    const int idx = iidx_t[(size_t)ib * KDIM + t];
    sm[L_VEC + 100 + t] = i_rowsum[idx];
    sm[L_VEC + 300 + t] = iscr[(size_t)ib * KDIM + t];
  }
  if (tid < 112) { const int sel = tid / 28, j = 100 + tid % 28; sm[L_PA + sel * 128 + j] = 0.f; }
  { const int j = tid & 127; sm[L_B1 + tid] = (j < 100) ? ((tid & 128) ? N2.b1[j] : N1.b1[j]) : 0.f; }
  if (tid < 128) { const int j = tid & 63; sm[L_B2 + tid] = (j < 50) ? ((tid & 64) ? N2.b2[j] : N1.b2[j]) : 0.f; }
  if (tid < 64)  { const int j = tid & 31; sm[L_B3 + tid] = (j < 25) ? ((tid & 32) ? N2.b3[j] : N1.b3[j]) : 0.f; }
  if (tid < 32)  { const int j = tid & 15; sm[L_B4 + tid] = (j < 12) ? ((tid & 16) ? N2.b4[j] : N1.b4[j]) : 0.f; }
  else if (tid < 64) { const int t = tid - 32; const int j = t & 15;
                       sm[L_W5 + t] = (j < 12) ? ((t & 16) ? N2.w5[j] : N1.w5[j]) : 0.f; }
  __syncthreads();

  // ---- phase 1: layer-1 projections (400 dots of length 100)
  for (int o = tid; o < 400; o += 256) {
    const int sel = o / 100, j = o % 100;
    const float* w1 = (sel < 2) ? N1.w1 : N2.w1;
    const int src = L_VEC + sel * 100;        // USUM, ISUM, US, IS in order
    const int rb = (sel & 1) * KDIM;
    float a0 = 0.f, a1 = 0.f, a2 = 0.f, a3 = 0.f;
    #pragma unroll 4
    for (int k = 0; k < KDIM; k += 4) {
      a0 = fmaf(sm[src + k + 0], w1[(size_t)(rb + k + 0) * KDIM + j], a0);
      a1 = fmaf(sm[src + k + 1], w1[(size_t)(rb + k + 1) * KDIM + j], a1);
      a2 = fmaf(sm[src + k + 2], w1[(size_t)(rb + k + 2) * KDIM + j], a2);
      a3 = fmaf(sm[src + k + 3], w1[(size_t)(rb + k + 3) * KDIM + j], a3);
    }
    sm[L_PA + sel * 128 + j] = (a0 + a1) + (a2 + a3);
  }
  __syncthreads();

  // ---- main loop: 2 nets x 2 M-halves (rows 0-63, 64-127; rows >=100 are pad)
  #pragma unroll
  for (int net = 0; net < 2; ++net) {
    const Weights W = net ? N2 : N1;
    // net0 (x1): h1[k][j] = relu(US[k]*PA1[j] + IS[k]*PB1[j] + b1[j])
    // net1 (x2): h1[k][j] = relu(USUM[k]*PA2[j] + ISUM[k]*PB2[j] + b1[j])
    const int vA  = net ? (L_VEC + 0)   : (L_VEC + 200);
    const int vB  = net ? (L_VEC + 100) : (L_VEC + 300);
    const int pAo = L_PA + (net ? 256 : 0);
    const int pBo = pAo + 128;
    const float bias2 = sm[L_B2 + net * 64 + 16 * wv + c16];
    const float bias3 = sm[L_B3 + net * 32 + 16 * (wv & 1) + c16];
    const float bias4 = sm[L_B4 + net * 16 + c16];
    const float wout  = sm[L_W5 + net * 16 + c16];
    const float b5v   = W.b5[0];

    // hoisted per-net frag-row inputs for h1 generation (this wave owns kstep=wv)
    float paf[8], pbf[8], b1f[8];
    {
      const int jb = 32 * wv + 8 * g;
      #pragma unroll
      for (int j2 = 0; j2 < 4; ++j2) {
        const f32x2 va = *(const f32x2*)&sm[pAo + jb + 2 * j2];
        const f32x2 vb = *(const f32x2*)&sm[pBo + jb + 2 * j2];
        const f32x2 v1 = *(const f32x2*)&sm[L_B1 + net * 128 + jb + 2 * j2];
        paf[2*j2] = va[0]; paf[2*j2+1] = va[1];
        pbf[2*j2] = vb[0]; pbf[2*j2+1] = vb[1];
        b1f[2*j2] = v1[0]; b1f[2*j2+1] = v1[1];
      }
    }

    #pragma unroll
    for (int hf = 0; hf < 2; ++hf) {
      const int row0 = 64 * hf;

      // ---- h1 A-fragment generation (wave wv = kstep wv, mtiles 0..3)
      #pragma unroll
      for (int m = 0; m < 4; ++m) {
        const int row = row0 + 16 * m + c16;
        const int rr = row < KDIM ? row : (KDIM - 1);   // clamp pad rows (M-pad garbage-safe)
        const float sA = sm[vA + rr], sB = sm[vB + rr];
        bf16x8 a;
        #pragma unroll
        for (int i = 0; i < 8; ++i)
          a[i] = (__bf16)fmaxf(fmaf(sA, paf[i], fmaf(sB, pbf[i], b1f[i])), 0.f);
        *(bf16x8*)((char*)sm + L_H1F * 4 + ((m * 4 + wv) * 64 + lane) * 16) = a;
      }
      __syncthreads();

      // ---- layer 2: h2[64x64] = relu(h1 @ W2 + b2); wave wv owns ntile wv
      #pragma unroll
      for (int m = 0; m < 4; ++m) {
        f32x4 acc = {0.f, 0.f, 0.f, 0.f};
        #pragma unroll
        for (int k = 0; k < 4; ++k) {
          const bf16x8 a = *(const bf16x8*)((const char*)sm + L_H1F * 4 + ((m * 4 + k) * 64 + lane) * 16);
          acc = __builtin_amdgcn_mfma_f32_16x16x32_bf16(a, W2f[net][k], acc, 0, 0, 0);
        }
        #pragma unroll
        for (int r = 0; r < 4; ++r)
          sm[L_H2 + (16 * m + 4 * g + r) * 66 + 16 * wv + c16] = fmaxf(acc[r] + bias2, 0.f);
      }
      __syncthreads();

      // ---- layer 3: h3 = relu(h2 @ W3 + b3); wave -> ntile wv&1, mtiles {2*(wv>>1)+mi}
      #pragma unroll
      for (int mi = 0; mi < 2; ++mi) {
        const int m = 2 * (wv >> 1) + mi;
        f32x4 acc = {0.f, 0.f, 0.f, 0.f};
        #pragma unroll
        for (int k = 0; k < 2; ++k) {
          bf16x8 a;
          #pragma unroll
          for (int j2 = 0; j2 < 4; ++j2) {
            const f32x2 v = *(const f32x2*)&sm[L_H2 + (16 * m + c16) * 66 + 32 * k + 8 * g + 2 * j2];
            a[2*j2]   = (__bf16)v[0];
            a[2*j2+1] = (__bf16)v[1];
          }
          acc = __builtin_amdgcn_mfma_f32_16x16x32_bf16(a, W3f[net][k], acc, 0, 0, 0);
        }
        #pragma unroll
        for (int r = 0; r < 4; ++r)
          sm[L_H3 + (16 * m + 4 * g + r) * 34 + 16 * (wv & 1) + c16] = fmaxf(acc[r] + bias3, 0.f);
      }
      __syncthreads();

      // ---- layer 4 + layer 5 + row-dot reduce; wave -> mtile wv
      {
        const int m = wv;
        f32x4 acc = {0.f, 0.f, 0.f, 0.f};
        bf16x8 a;
        #pragma unroll
        for (int j2 = 0; j2 < 4; ++j2) {
          const f32x2 v = *(const f32x2*)&sm[L_H3 + (16 * m + c16) * 34 + 8 * g + 2 * j2];
          a[2*j2]   = (__bf16)v[0];
          a[2*j2+1] = (__bf16)v[1];
        }
        acc = __builtin_amdgcn_mfma_f32_16x16x32_bf16(a, W4f[net], acc, 0, 0, 0);
        float s[4];
        #pragma unroll
        for (int r = 0; r < 4; ++r) {
          float v = fmaxf(acc[r] + bias4, 0.f) * wout;   // relu(h4)*w5[col], pads contribute 0
          v += __shfl_xor(v, 1); v += __shfl_xor(v, 2);
          v += __shfl_xor(v, 4); v += __shfl_xor(v, 8);
          s[r] = v;
        }
        if (c16 == 0) {
          const int rbase = L_C + net * 128 + row0 + 16 * m + 4 * g;
          sm[rbase + 0] = s[0] + b5v;
          sm[rbase + 1] = s[1] + b5v;
          sm[rbase + 2] = s[2] + b5v;
          sm[rbase + 3] = s[3] + b5v;
        }
      }
      // no barrier needed here: next h1F-gen only conflicts with L2 reads,
      // which all waves finished before the post-L2 barrier.
    }
  }
  __syncthreads();

  // ---- final: sum valid rows (0..99) of both nets -> sigmoid(mean)
  if (tid < 64) {
    float v = sm[L_C + tid] + sm[L_C + 128 + tid];
    if (tid + 64 < KDIM) v += sm[L_C + tid + 64] + sm[L_C + 128 + tid + 64];
    #pragma unroll
    for (int d = 1; d < 64; d <<= 1) v += __shfl_xor(v, d);
    if (tid == 0) out[b] = 1.f / (1.f + expf(-0.01f * v));
  }
}

extern "C" void kernel_launch(void* const* d_in, const int* in_sizes, int n_in,
                              void* d_out, int out_size, void* d_ws, size_t ws_size,
                              hipStream_t stream) {
  const int*   user_idxs = (const int*)d_in[0];
  const int*   item_idxs = (const int*)d_in[1];
  const int*   uidx_t    = (const int*)d_in[2];
  const int*   iidx_t    = (const int*)d_in[3];
  const float* uscr      = (const float*)d_in[4];
  const float* iscr      = (const float*)d_in[5];
  const float* uemb      = (const float*)d_in[6];
  const float* iemb      = (const float*)d_in[7];

  const int B  = in_sizes[0];
  const int NU = in_sizes[6] / DDIM;
  const int NI = in_sizes[7] / DDIM;

  Weights N1 { (const float*)d_in[8],  (const float*)d_in[9],
               (const float*)d_in[10], (const float*)d_in[11],
               (const float*)d_in[12], (const float*)d_in[13],
               (const float*)d_in[14], (const float*)d_in[15],
               (const float*)d_in[16], (const float*)d_in[17] };
  Weights N2 { (const float*)d_in[18], (const float*)d_in[19],
               (const float*)d_in[20], (const float*)d_in[21],
               (const float*)d_in[22], (const float*)d_in[23],
               (const float*)d_in[24], (const float*)d_in[25],
               (const float*)d_in[26], (const float*)d_in[27] };

  float* u_rowsum = (float*)d_ws;
  float* i_rowsum = u_rowsum + NU;
  float* out = (float*)d_out;

  rowsum_kernel<<<1024, 256, 0, stream>>>(uemb, iemb, u_rowsum, i_rowsum, NU, NI);
  mlp_kernel<<<B, 256, 0, stream>>>(user_idxs, item_idxs, uidx_t, iidx_t,
                                    uscr, iscr, u_rowsum, i_rowsum, N1, N2, out);
}

// Round 6
// 93.883 us; speedup vs baseline: 2.4243x; 2.4243x over previous
//
#include <hip/hip_runtime.h>
#include <math.h>

#define KDIM 100
#define DDIM 64

typedef __bf16 bf16x8 __attribute__((ext_vector_type(8)));
typedef float  f32x4  __attribute__((ext_vector_type(4)));

struct Weights {
  const float *w1, *b1, *w2, *b2, *w3, *b3, *w4, *b4, *w5, *b5;
};

// ---------------- LDS layout ----------------
constexpr int L_VEC = 0;      // [4][100] USUM, ISUM, US, IS
constexpr int L_PA  = 400;    // [4][128] PA1,PB1,PA2,PB2 (cols 100-127 zeroed)
constexpr int L_B1  = 912;    // [2][128]
constexpr int L_B2  = 1168;   // [2][64]
constexpr int L_B3  = 1296;   // [2][32]
constexpr int L_B4  = 1360;   // [2][16]
constexpr int L_W5  = 1392;   // [2][16]
constexpr int L_C   = 1424;   // [2][128] per-net per-row outputs
constexpr int SM_F  = 1680;
constexpr int H2T_BYTE   = SM_F * 4;                    // 6720 (16B aligned)
constexpr int H2T_WBYTES = 32 * 72 * 2;                 // 4608 per wave
constexpr int H3T_BYTE   = H2T_BYTE + 8 * H2T_WBYTES;   // 43584
constexpr int H3T_WBYTES = 32 * 40 * 2;                 // 2560 per wave
constexpr int SM_BYTES   = H3T_BYTE + 8 * H3T_WBYTES;   // 64064 B

// ---------------- kernel 1: rowsums + weight-fragment packing ----------------
// wfrag layout: [net(2)][frag f(21)][lane(64)][8 bf16].  f: 0-15 = W2 (k*4+n),
// 16-19 = W3 (k*2+n), 20 = W4.  B-frag elem i: B[kk][nn] per R5-verified layout.
__global__ void prep_kernel(const float* __restrict__ user_emb,
                            const float* __restrict__ item_emb,
                            float* __restrict__ u_rowsum,
                            float* __restrict__ i_rowsum,
                            int NU, int NI, Weights N1, Weights N2,
                            __bf16* __restrict__ wfrag) {
  const int tid  = threadIdx.x;
  const int lane = tid & 63;
  const int g = lane >> 4, c16 = lane & 15;
  const int gw = (blockIdx.x * blockDim.x + tid) >> 6;

  if (gw < 42) {
    const int net = gw / 21, f = gw % 21;
    const Weights W = net ? N2 : N1;
    bf16x8 v;
    if (f < 16) {
      const int k = f >> 2, n = f & 3;
      #pragma unroll
      for (int i = 0; i < 8; ++i) {
        const int kk = 32 * k + 8 * g + i, nn = 16 * n + c16;
        v[i] = (__bf16)((kk < 100 && nn < 50) ? W.w2[kk * 50 + nn] : 0.f);
      }
    } else if (f < 20) {
      const int t = f - 16, k = t >> 1, n = t & 1;
      #pragma unroll
      for (int i = 0; i < 8; ++i) {
        const int kk = 32 * k + 8 * g + i, nn = 16 * n + c16;
        v[i] = (__bf16)((kk < 50 && nn < 25) ? W.w3[kk * 25 + nn] : 0.f);
      }
    } else {
      #pragma unroll
      for (int i = 0; i < 8; ++i) {
        const int kk = 8 * g + i, nn = c16;
        v[i] = (__bf16)((kk < 25 && nn < 12) ? W.w4[kk * 12 + nn] : 0.f);
      }
    }
    *(bf16x8*)(wfrag + (size_t)gw * 512 + lane * 8) = v;
  }

  // coalesced rowsums: wave = 4 rows
  const int NR = NU + NI;
  const int chunk = lane & 15, lrow = lane >> 4;
  const int nwave = (gridDim.x * blockDim.x) >> 6;
  for (int base = gw * 4; base < NR; base += nwave * 4) {
    const int r = base + lrow;
    float s = 0.f;
    if (r < NR) {
      const float* src = (r < NU) ? (user_emb + (size_t)r * DDIM)
                                  : (item_emb + (size_t)(r - NU) * DDIM);
      const float4 v4 = ((const float4*)src)[chunk];
      s = v4.x + v4.y + v4.z + v4.w;
    }
    s += __shfl_xor(s, 1); s += __shfl_xor(s, 2);
    s += __shfl_xor(s, 4); s += __shfl_xor(s, 8);
    if (chunk == 0 && r < NR) {
      if (r < NU) u_rowsum[r] = s; else i_rowsum[r - NU] = s;
    }
  }
}

// ---------------- kernel 2: barrier-free per-wave MFMA chain ----------------
// 512 threads = 8 waves; wave wv: net = wv>>2, quarter q = wv&3 (rows 25q..25q+24).
__global__ void __launch_bounds__(512, 4) mlp_kernel(
    const int* __restrict__ user_idxs, const int* __restrict__ item_idxs,
    const int* __restrict__ uidx_t, const int* __restrict__ iidx_t,
    const float* __restrict__ uscr, const float* __restrict__ iscr,
    const float* __restrict__ u_rowsum, const float* __restrict__ i_rowsum,
    const float* __restrict__ n1w1, const float* __restrict__ n2w1,
    const float* __restrict__ n1b5, const float* __restrict__ n2b5,
    const __bf16* __restrict__ wfrag, float* __restrict__ out)
{
  __shared__ __align__(16) char smem[SM_BYTES];
  float* sm = (float*)smem;
  const int tid  = threadIdx.x;
  const int lane = tid & 63;
  const int wv   = tid >> 6;
  const int g    = lane >> 4;
  const int c16  = lane & 15;
  const int b    = blockIdx.x;

  // ---- phase 0: gathers + bias staging + pad zeroing
  if (tid < KDIM) {
    const int ub = user_idxs[b];
    const int idx = uidx_t[(size_t)ub * KDIM + tid];
    sm[L_VEC + 0 + tid]   = u_rowsum[idx];
    sm[L_VEC + 200 + tid] = uscr[(size_t)ub * KDIM + tid];
  } else if (tid >= 128 && tid < 128 + KDIM) {
    const int t = tid - 128;
    const int ib = item_idxs[b];
    const int idx = iidx_t[(size_t)ib * KDIM + t];
    sm[L_VEC + 100 + t] = i_rowsum[idx];
    sm[L_VEC + 300 + t] = iscr[(size_t)ib * KDIM + t];
  }
  if (tid >= 256 && tid < 368) {
    const int t = tid - 256;
    const int sel = t / 28, j = 100 + t % 28;
    sm[L_PA + sel * 128 + j] = 0.f;
  }
  {
    const Weights* dummy = nullptr; (void)dummy;
  }
  if (tid < 256) {
    const int j = tid & 127;
    const float* b1p = (tid & 128) ? (n2w1 ? nullptr : nullptr) : nullptr;
    (void)b1p;
  }
  __syncthreads();  // placeholder barrier removed below; real staging next
  // NOTE: bias staging needs the bias pointers; they ride in via wfrag-adjacent
  // constant staging done in phase 0b below using global pointers passed in
  // through the Weights-free signature: biases were pre-packed into wfrag tail.
  // ---- phase 1: layer-1 projections
  for (int o = tid; o < 400; o += 512) {
    const int sel = o / 100, j = o % 100;
    const float* w1 = (sel < 2) ? n1w1 : n2w1;
    const int src = L_VEC + sel * 100;
    const int rb = (sel & 1) * KDIM;
    float a0 = 0.f, a1 = 0.f, a2 = 0.f, a3 = 0.f;
    #pragma unroll 4
    for (int k = 0; k < KDIM; k += 4) {
      a0 = fmaf(sm[src + k + 0], w1[(size_t)(rb + k + 0) * KDIM + j], a0);
      a1 = fmaf(sm[src + k + 1], w1[(size_t)(rb + k + 1) * KDIM + j], a1);
      a2 = fmaf(sm[src + k + 2], w1[(size_t)(rb + k + 2) * KDIM + j], a2);
      a3 = fmaf(sm[src + k + 3], w1[(size_t)(rb + k + 3) * KDIM + j], a3);
    }
    sm[L_PA + sel * 128 + j] = (a0 + a1) + (a2 + a3);
  }
  // bias staging from the packed tail of wfrag (f32 values stored after frags):
  // tail layout (floats): [2][128] b1 | [2][64] b2 | [2][32] b3 | [2][16] b4 | [2][16] w5
  {
    const float* tail = (const float*)(wfrag + (size_t)42 * 512);
    if (tid < 256)      sm[L_B1 + tid] = tail[tid];
    else if (tid < 384) sm[L_B2 + (tid - 256)] = tail[256 + (tid - 256)];
    else if (tid < 448) sm[L_B3 + (tid - 384)] = tail[384 + (tid - 384)];
    else if (tid < 480) sm[L_B4 + (tid - 448)] = tail[448 + (tid - 448)];
    else                sm[L_W5 + (tid - 480)] = tail[480 + (tid - 480)];
  }
  __syncthreads();

  // ---- per-wave independent MFMA chain
  const int net = wv >> 2;
  const int q   = wv & 3;
  const int r0  = 25 * q;
  const int vA  = net ? (L_VEC + 0)   : (L_VEC + 200);
  const int vB  = net ? (L_VEC + 100) : (L_VEC + 300);
  const int pAo = L_PA + net * 256;
  const int pBo = pAo + 128;
  __bf16* h2t = (__bf16*)(smem + H2T_BYTE + wv * H2T_WBYTES);  // [32][72]
  __bf16* h3t = (__bf16*)(smem + H3T_BYTE + wv * H3T_WBYTES);  // [32][40]
  const bf16x8* WF = (const bf16x8*)wfrag;
  const int fb = net * 21;
  const float b5v = net ? n2b5[0] : n1b5[0];

  // row scalars (clamped; pad rows filtered at the L_C write)
  float sAr[2], sBr[2];
  #pragma unroll
  for (int m = 0; m < 2; ++m) {
    const int row = r0 + 16 * m + c16;
    const int rr = row < KDIM ? row : (KDIM - 1);
    sAr[m] = sm[vA + rr]; sBr[m] = sm[vB + rr];
  }

  // ---- layer 2: h2[32x64] = relu(h1 @ W2 + b2), h1 generated in-register
  f32x4 acc2[2][4];
  #pragma unroll
  for (int m = 0; m < 2; ++m)
    #pragma unroll
    for (int n = 0; n < 4; ++n) acc2[m][n] = (f32x4){0.f, 0.f, 0.f, 0.f};

  #pragma unroll
  for (int k = 0; k < 4; ++k) {
    bf16x8 bw[4];
    #pragma unroll
    for (int n = 0; n < 4; ++n) bw[n] = WF[(size_t)(fb + k * 4 + n) * 64 + lane];
    const int jb = 32 * k + 8 * g;
    float paf[8], pbf[8], b1f[8];
    #pragma unroll
    for (int i = 0; i < 8; ++i) {
      paf[i] = sm[pAo + jb + i];
      pbf[i] = sm[pBo + jb + i];
      b1f[i] = sm[L_B1 + net * 128 + jb + i];
    }
    #pragma unroll
    for (int m = 0; m < 2; ++m) {
      bf16x8 a;
      #pragma unroll
      for (int i = 0; i < 8; ++i)
        a[i] = (__bf16)fmaxf(fmaf(sAr[m], paf[i], fmaf(sBr[m], pbf[i], b1f[i])), 0.f);
      #pragma unroll
      for (int n = 0; n < 4; ++n)
        acc2[m][n] = __builtin_amdgcn_mfma_f32_16x16x32_bf16(a, bw[n], acc2[m][n], 0, 0, 0);
    }
  }
  // epilogue -> h2t bf16 [row][col], stride 72
  #pragma unroll
  for (int m = 0; m < 2; ++m)
    #pragma unroll
    for (int n = 0; n < 4; ++n) {
      const float b2v = sm[L_B2 + net * 64 + 16 * n + c16];
      #pragma unroll
      for (int r = 0; r < 4; ++r)
        h2t[(16 * m + 4 * g + r) * 72 + 16 * n + c16] =
            (__bf16)fmaxf(acc2[m][n][r] + b2v, 0.f);
    }
  asm volatile("s_waitcnt lgkmcnt(0)" ::: "memory");
  __builtin_amdgcn_sched_barrier(0);

  // ---- layer 3: h3[32x32] = relu(h2 @ W3 + b3)
  bf16x8 W3f[2][2];
  #pragma unroll
  for (int k = 0; k < 2; ++k)
    #pragma unroll
    for (int n = 0; n < 2; ++n)
      W3f[k][n] = WF[(size_t)(fb + 16 + k * 2 + n) * 64 + lane];
  f32x4 acc3[2][2];
  #pragma unroll
  for (int m = 0; m < 2; ++m)
    #pragma unroll
    for (int n = 0; n < 2; ++n) acc3[m][n] = (f32x4){0.f, 0.f, 0.f, 0.f};
  #pragma unroll
  for (int m = 0; m < 2; ++m)
    #pragma unroll
    for (int k = 0; k < 2; ++k) {
      const bf16x8 a = *(const bf16x8*)(h2t + (16 * m + c16) * 72 + 32 * k + 8 * g);
      #pragma unroll
      for (int n = 0; n < 2; ++n)
        acc3[m][n] = __builtin_amdgcn_mfma_f32_16x16x32_bf16(a, W3f[k][n], acc3[m][n], 0, 0, 0);
    }
  #pragma unroll
  for (int m = 0; m < 2; ++m)
    #pragma unroll
    for (int n = 0; n < 2; ++n) {
      const float b3v = sm[L_B3 + net * 32 + 16 * n + c16];
      #pragma unroll
      for (int r = 0; r < 4; ++r)
        h3t[(16 * m + 4 * g + r) * 40 + 16 * n + c16] =
            (__bf16)fmaxf(acc3[m][n][r] + b3v, 0.f);
    }
  asm volatile("s_waitcnt lgkmcnt(0)" ::: "memory");
  __builtin_amdgcn_sched_barrier(0);

  // ---- layer 4 + layer 5 + per-row reduce
  {
    const bf16x8 W4f = WF[(size_t)(fb + 20) * 64 + lane];
    const float b4v = sm[L_B4 + net * 16 + c16];
    const float w5v = sm[L_W5 + net * 16 + c16];
    #pragma unroll
    for (int m = 0; m < 2; ++m) {
      const bf16x8 a = *(const bf16x8*)(h3t + (16 * m + c16) * 40 + 8 * g);
      const f32x4 z = {0.f, 0.f, 0.f, 0.f};
      const f32x4 acc4 = __builtin_amdgcn_mfma_f32_16x16x32_bf16(a, W4f, z, 0, 0, 0);
      #pragma unroll
      for (int r = 0; r < 4; ++r) {
        float v = fmaxf(acc4[r] + b4v, 0.f) * w5v;   // col pads contribute 0
        v += __shfl_xor(v, 1); v += __shfl_xor(v, 2);
        v += __shfl_xor(v, 4); v += __shfl_xor(v, 8);
        const int lrow = 16 * m + 4 * g + r;
        if (c16 == 0 && lrow < 25)
          sm[L_C + net * 128 + r0 + lrow] = v + b5v;
      }
    }
  }
  __syncthreads();

  // ---- final: sum rows 0..99 of both nets -> sigmoid(mean)
  float v = 0.f;
  if (tid < KDIM) v = sm[L_C + tid] + sm[L_C + 128 + tid];
  if (tid < 128) {
    #pragma unroll
    for (int d = 1; d < 64; d <<= 1) v += __shfl_xor(v, d);
    if ((tid & 63) == 0) sm[tid >> 6] = v;
  }
  __syncthreads();
  if (tid == 0) out[b] = 1.f / (1.f + expf(-0.01f * (sm[0] + sm[1])));
}

// ---------------- kernel 1b: pack bias tail into wfrag ----------------
__global__ void bias_pack_kernel(Weights N1, Weights N2, float* __restrict__ tail) {
  const int tid = threadIdx.x;  // 512 threads, 1 block
  if (tid < 256) {
    const int j = tid & 127; const Weights W = (tid & 128) ? N2 : N1;
    tail[tid] = (j < 100) ? W.b1[j] : 0.f;
  } else if (tid < 384) {
    const int t = tid - 256; const int j = t & 63; const Weights W = (t & 64) ? N2 : N1;
    tail[256 + t] = (j < 50) ? W.b2[j] : 0.f;
  } else if (tid < 448) {
    const int t = tid - 384; const int j = t & 31; const Weights W = (t & 32) ? N2 : N1;
    tail[384 + t] = (j < 25) ? W.b3[j] : 0.f;
  } else if (tid < 480) {
    const int t = tid - 448; const int j = t & 15; const Weights W = (t & 16) ? N2 : N1;
    tail[448 + t] = (j < 12) ? W.b4[j] : 0.f;
  } else {
    const int t = tid - 480; const int j = t & 15; const Weights W = (t & 16) ? N2 : N1;
    tail[480 + t] = (j < 12) ? W.w5[j] : 0.f;
  }
}

extern "C" void kernel_launch(void* const* d_in, const int* in_sizes, int n_in,
                              void* d_out, int out_size, void* d_ws, size_t ws_size,
                              hipStream_t stream) {
  const int*   user_idxs = (const int*)d_in[0];
  const int*   item_idxs = (const int*)d_in[1];
  const int*   uidx_t    = (const int*)d_in[2];
  const int*   iidx_t    = (const int*)d_in[3];
  const float* uscr      = (const float*)d_in[4];
  const float* iscr      = (const float*)d_in[5];
  const float* uemb      = (const float*)d_in[6];
  const float* iemb      = (const float*)d_in[7];

  const int B  = in_sizes[0];
  const int NU = in_sizes[6] / DDIM;
  const int NI = in_sizes[7] / DDIM;

  Weights N1 { (const float*)d_in[8],  (const float*)d_in[9],
               (const float*)d_in[10], (const float*)d_in[11],
               (const float*)d_in[12], (const float*)d_in[13],
               (const float*)d_in[14], (const float*)d_in[15],
               (const float*)d_in[16], (const float*)d_in[17] };
  Weights N2 { (const float*)d_in[18], (const float*)d_in[19],
               (const float*)d_in[20], (const float*)d_in[21],
               (const float*)d_in[22], (const float*)d_in[23],
               (const float*)d_in[24], (const float*)d_in[25],
               (const float*)d_in[26], (const float*)d_in[27] };

  float* u_rowsum = (float*)d_ws;
  float* i_rowsum = u_rowsum + NU;
  const size_t wsoff = (((size_t)(NU + NI) * 4 + 1023) & ~(size_t)1023);
  __bf16* wfrag = (__bf16*)((char*)d_ws + wsoff);          // 42*512 bf16 frags
  float*  tail  = (float*)(wfrag + (size_t)42 * 512);      // 512 f32 bias tail
  float* out = (float*)d_out;

  prep_kernel<<<1024, 256, 0, stream>>>(uemb, iemb, u_rowsum, i_rowsum, NU, NI, N1, N2, wfrag);
  bias_pack_kernel<<<1, 512, 0, stream>>>(N1, N2, tail);
  mlp_kernel<<<B, 512, 0, stream>>>(user_idxs, item_idxs, uidx_t, iidx_t,
                                    uscr, iscr, u_rowsum, i_rowsum,
                                    N1.w1, N2.w1, N1.b5, N2.b5, wfrag, out);
}